// Round 6
// baseline (492.973 us; speedup 1.0000x reference)
//
#include <hip/hip_runtime.h>

// ---- shapes (hard-coded to this problem) ----
#define TT 64
#define SLOT 320          // OUT + ACT
#define CONCAT 1536       // IN + 4*SLOT
#define XROW 520          // ugemm staging row: 512 + 8 pad

typedef __attribute__((ext_vector_type(8))) short bf16x8;
typedef __attribute__((ext_vector_type(4))) short short4v;
typedef __attribute__((ext_vector_type(4))) float float4v;

// flags are the ONLY atomics; data moves as plain vectorized loads/stores
// bracketed by agent-scope release/acquire fences (wbl2/inv on gfx950).
#define AL(p)    __hip_atomic_load((p), __ATOMIC_RELAXED, __HIP_MEMORY_SCOPE_AGENT)
#define AS(p, v) __hip_atomic_store((p), (v), __ATOMIC_RELAXED, __HIP_MEMORY_SCOPE_AGENT)
#define FENCE_ACQ() __builtin_amdgcn_fence(__ATOMIC_ACQUIRE, "agent")
#define FENCE_REL() __builtin_amdgcn_fence(__ATOMIC_RELEASE, "agent")
#define SPIN_PAUSE __builtin_amdgcn_s_sleep(2)

__device__ __forceinline__ short f2bf(float f) {
    union { float f; unsigned u; } v;
    v.f = f;
    unsigned r = v.u + 0x7fffu + ((v.u >> 16) & 1u);  // RNE
    return (short)(r >> 16);
}

// Repack W (256 x 1536 fp32) into bf16 MFMA-B-fragment streams:
//  sec 0..3 (64K shorts each): tap h=sec+1 -> A_h = W[:, (3-sec)*320 .. +255]
//                              [tl 0..15][kb 0..7][lane][8]
//  Wao at short offset 262144: [tl 0..15][kb 0..15][lane][8] over a-hist+o cols
// Also resets the sync flags (runs before hist on the same stream).
__global__ void wprep_kernel(const float* __restrict__ W, short* __restrict__ Wb,
                             unsigned* __restrict__ flags) {
    if (blockIdx.x == 0) {
        for (int i = threadIdx.x; i < 1024; i += 256) flags[i] = 0u;
    }
    int idx = blockIdx.x * 256 + threadIdx.x;       // 0 .. 49151
    if (idx >= 49152) return;
    int lane = idx & 63;
    int q = lane >> 4, ln = lane & 15;
    int n, col;
    if (idx < 32768) {              // tap sections
        int sec = idx >> 13;                        // 0..3
        int rem = idx & 8191;
        int tl = rem >> 9, kb = (rem >> 6) & 7;
        n = tl * 16 + ln;
        col = (3 - sec) * SLOT + kb * 32 + q * 8;   // A_1 at 960, A_4 at 0
    } else {                        // ao-part (for ugemm)
        int idx3 = idx - 32768;
        int tl = idx3 >> 10, kb = (idx3 >> 6) & 15;
        n = tl * 16 + ln;
        int ka = kb * 32 + q * 8;                   // 0..511
        col = (ka < 256) ? ((ka >> 6) * SLOT + 256 + (ka & 63))  // a-slot cols
                         : (1024 + ka);                          // o cols 1280..
    }
    const float* src = W + (size_t)n * CONCAT + col;
    short4v s0, s1;
    s0.x = f2bf(src[0]); s0.y = f2bf(src[1]); s0.z = f2bf(src[2]); s0.w = f2bf(src[3]);
    s1.x = f2bf(src[4]); s1.y = f2bf(src[5]); s1.z = f2bf(src[6]); s1.w = f2bf(src[7]);
    short* dst = Wb + (size_t)idx * 8;
    *(short4v*)dst = s0;
    *(short4v*)(dst + 4) = s1;
}

// Parallel precompute: u = W_ao * [a_hist | o] + b for ALL 65536 tokens, written
// into out (sequential kernel reads u then overwrites with z in-place).
__global__ __launch_bounds__(256) void ugemm_kernel(
    const float* __restrict__ o,    // (B,T,P,256)
    const float* __restrict__ act,  // (B,T,P,64)
    const float* __restrict__ bias, // (256)
    const short* __restrict__ Wb,   // tap secs + Wao
    float* __restrict__ out)        // (B,T,P,256) <- u
{
    __shared__ short xp[64 * XROW];   // 66560 B

    const int tid = threadIdx.x;
    const int wg  = blockIdx.x;       // b = wg>>6, t = wg&63
    const int b   = wg >> 6, t = wg & 63;
    const size_t tau0 = (size_t)wg * 64;

#pragma unroll
    for (int h = 0; h < 4; ++h) {
        int tp = t - 4 + h;
        const float* ap = act + (((size_t)b * 64 + tp) * 64) * 64;
        for (int f = tid; f < 1024; f += 256) {
            int p = f >> 4, c4 = (f & 15) << 2;
            short4v s;
            if (tp >= 0) {
                float4v v = *(const float4v*)(ap + p * 64 + c4);
                s.x = f2bf(v.x); s.y = f2bf(v.y); s.z = f2bf(v.z); s.w = f2bf(v.w);
            } else { s.x = 0; s.y = 0; s.z = 0; s.w = 0; }
            *(short4v*)&xp[p * XROW + h * 64 + c4] = s;
        }
    }
    {
        const float* op = o + tau0 * 256;
        for (int f = tid; f < 4096; f += 256) {
            int p = f >> 6, c4 = (f & 63) << 2;
            float4v v = *(const float4v*)(op + p * 256 + c4);
            short4v s;
            s.x = f2bf(v.x); s.y = f2bf(v.y); s.z = f2bf(v.z); s.w = f2bf(v.w);
            *(short4v*)&xp[p * XROW + 256 + c4] = s;
        }
    }
    __syncthreads();

    const int wv = tid >> 6, lane = tid & 63, q = lane >> 4, ln = lane & 15;
    const short* wao = Wb + 262144;

    float4v acc[4][4];
#pragma unroll
    for (int m = 0; m < 4; ++m)
#pragma unroll
        for (int i = 0; i < 4; ++i)
            acc[m][i] = (float4v){0.f, 0.f, 0.f, 0.f};

#pragma unroll
    for (int kb = 0; kb < 16; ++kb) {
        bf16x8 bf[4];
#pragma unroll
        for (int i = 0; i < 4; ++i)
            bf[i] = *(const bf16x8*)(wao + (((size_t)(4 * wv + i) * 16 + kb) * 64 + lane) * 8);
#pragma unroll
        for (int m = 0; m < 4; ++m) {
            bf16x8 af = *(const bf16x8*)&xp[(m * 16 + ln) * XROW + kb * 32 + q * 8];
#pragma unroll
            for (int i = 0; i < 4; ++i)
                acc[m][i] = __builtin_amdgcn_mfma_f32_16x16x32_bf16(af, bf[i], acc[m][i], 0, 0, 0);
        }
    }

#pragma unroll
    for (int i = 0; i < 4; ++i) {
        float bv = bias[(4 * wv + i) * 16 + ln];
#pragma unroll
        for (int m = 0; m < 4; ++m)
#pragma unroll
            for (int r = 0; r < 4; ++r)
                out[(tau0 + m * 16 + q * 4 + r) * 256 + (4 * wv + i) * 16 + ln] = acc[m][i][r] + bv;
    }
}

// Sequential kernel, 2-WG teams (128 WGs total, 1 WG/CU via 90KB LDS).
// team = blk&63 (16 seqs), role = blk>>6: 0 = FRONT (A1,A2 resident; z(t-1),z(t-2)
// from own LDS history), 1 = HELPER (A3,A4 resident; stages z(t-3) from global with
// 3 steps of slack, keeps z(t-4) in LDS double-buffer, folds u(t); publishes
// P34(t) = A3 z(t-3) + A4 z(t-4) + u(t) through a depth-4 ring).
// Flags (per team): fl[0] = front z-step count, fl[1] = helper P count.
// Data: plain float4 ld/st; flags: relaxed atomics + agent release/acquire fences.
// Ring depth 4 safe: helper waited fl[0] >= t-2 => front finished t-3 => slot t&3
// consumed. Helper reads u(t) before publishing P(t), front overwrites u(t) with
// z(t) only after consuming P(t) -> no u/z race. Acyclic waits -> no deadlock.
__global__ __launch_bounds__(1024, 4) void hist_kernel(
    const short* __restrict__ Wpk,
    unsigned* __restrict__ flags,
    float* __restrict__ pring,
    float* out)
{
    __shared__ short lds[45056];   // 90112 B: forces 1 WG/CU (co-residency guarantee)

    const int tid  = threadIdx.x;
    const int wave = tid >> 6;
    const int lane = tid & 63;
    const int q    = lane >> 4;
    const int ln   = lane & 15;
    const int team = blockIdx.x & 63;
    const int role = blockIdx.x >> 6;          // 0=front 1=helper
    const int bb   = team >> 2;
    const int p0   = (team & 3) << 4;
    unsigned* fl = flags + team * 16;
    float* outb = out + (((size_t)bb * 64) * 64 + p0) * 256;
    float* ring = pring + (size_t)team * 16384;   // 4 slots x 4096 floats
    const int n = (wave << 4) + ln;
    const int arow = ln * 520 + (q << 3);

    // resident tap matrices: role 0 -> A1,A2 (secs 0,1); role 1 -> A3,A4 (secs 2,3)
    // wave holds N-tile 'wave' x K=256 per tap: 16 frags = 64 VGPR
    bf16x8 wres[16];
    {
        const short* wp = Wpk + (size_t)(role * 2) * 65536
                              + ((size_t)(wave * 8) * 64 + lane) * 8;
#pragma unroll
        for (int kb = 0; kb < 8; ++kb) {
            wres[kb]     = *(const bf16x8*)(wp + kb * 512);
            wres[kb + 8] = *(const bf16x8*)(wp + 65536 + kb * 512);
        }
    }

    // zero the [16 rows][2 slots x 256 + 8 pad] bf16 history/staging region
    for (int i = tid; i < 4160; i += 1024) ((float*)lds)[i] = 0.f;
    __syncthreads();

    if (role == 0) {
        // ---------------- FRONT: z(t) = A1 z(t-1) + A2 z(t-2) + P34(t) ----------------
        for (int t = 0; t < TT; ++t) {
            const int s1 = ((t + 1) & 1) << 8;   // slot of z(t-1)
            const int s2 = (t & 1) << 8;         // slot of z(t-2) (rewritten with z(t))
            float4v a0 = {0.f, 0.f, 0.f, 0.f}, a1 = a0;
#pragma unroll
            for (int kb = 0; kb < 8; kb += 2) {
                bf16x8 f0 = *(const bf16x8*)&lds[arow + s1 + kb * 32];
                bf16x8 f1 = *(const bf16x8*)&lds[arow + s1 + (kb + 1) * 32];
                a0 = __builtin_amdgcn_mfma_f32_16x16x32_bf16(f0, wres[kb],     a0, 0, 0, 0);
                a1 = __builtin_amdgcn_mfma_f32_16x16x32_bf16(f1, wres[kb + 1], a1, 0, 0, 0);
            }
#pragma unroll
            for (int kb = 0; kb < 8; kb += 2) {
                bf16x8 f0 = *(const bf16x8*)&lds[arow + s2 + kb * 32];
                bf16x8 f1 = *(const bf16x8*)&lds[arow + s2 + (kb + 1) * 32];
                a0 = __builtin_amdgcn_mfma_f32_16x16x32_bf16(f0, wres[8 + kb],     a0, 0, 0, 0);
                a1 = __builtin_amdgcn_mfma_f32_16x16x32_bf16(f1, wres[8 + kb + 1], a1, 0, 0, 0);
            }
            if (tid == 0) {
                while (AL(&fl[1]) < (unsigned)(t + 1)) SPIN_PAUSE;
                FENCE_ACQ();
            }
            __syncthreads();   // P visible; all A-reads of slot s2 done
            const float4v P = *(const float4v*)&ring[(size_t)(t & 3) * 4096 + (tid << 2)];
            float4v z = (a0 + a1) + P;
            float* outp = outb + (size_t)t * 16384;
#pragma unroll
            for (int r = 0; r < 4; ++r) {
                const int m = (q << 2) + r;
                outp[m * 256 + n] = z[r];                 // plain store
                lds[m * 520 + s2 + n] = f2bf(z[r]);       // z(t) -> slot t&1
            }
            __syncthreads();   // drains z stores (vmcnt 0) + orders LDS for next step
            if (tid == 0) {
                FENCE_REL();
                AS(&fl[0], (unsigned)(t + 1));
            }
        }
    } else {
        // ---------------- HELPER: P34(t) = A3 z(t-3) + A4 z(t-4) + u(t) ----------------
        for (int t = 0; t < TT; ++t) {
            // read u(t) (plain; precedes P(t) publish, so precedes front's z(t) write)
            const float* up = outb + (size_t)t * 16384;
            float uu[4];
#pragma unroll
            for (int r = 0; r < 4; ++r) uu[r] = up[((q << 2) + r) * 256 + n];

            if (t >= 3) {
                if (tid == 0) {
                    while (AL(&fl[0]) < (unsigned)(t - 2)) SPIN_PAUSE;   // z(t-3) ready
                    FENCE_ACQ();
                }
                __syncthreads();
                // stage z(t-3) -> LDS slot (t-3)&1 (bf16); z(t-4) kept from last step
                const float* zp = outb + (size_t)(t - 3) * 16384;
                const int row = tid >> 6, c4 = (tid & 63) << 2;
                float4v zv = *(const float4v*)(zp + row * 256 + c4);
                short4v s;
                s.x = f2bf(zv.x); s.y = f2bf(zv.y); s.z = f2bf(zv.z); s.w = f2bf(zv.w);
                *(short4v*)&lds[row * 520 + (((t - 3) & 1) << 8) + c4] = s;
            }
            __syncthreads();   // staged z visible to all waves

            const int s3 = ((t + 1) & 1) << 8;   // slot of z(t-3)  ((t-3)&1 == (t+1)&1)
            const int s4 = (t & 1) << 8;         // slot of z(t-4)
            float4v a0 = {0.f, 0.f, 0.f, 0.f}, a1 = a0;
#pragma unroll
            for (int kb = 0; kb < 8; kb += 2) {
                bf16x8 f0 = *(const bf16x8*)&lds[arow + s3 + kb * 32];
                bf16x8 f1 = *(const bf16x8*)&lds[arow + s3 + (kb + 1) * 32];
                a0 = __builtin_amdgcn_mfma_f32_16x16x32_bf16(f0, wres[kb],     a0, 0, 0, 0);
                a1 = __builtin_amdgcn_mfma_f32_16x16x32_bf16(f1, wres[kb + 1], a1, 0, 0, 0);
            }
#pragma unroll
            for (int kb = 0; kb < 8; kb += 2) {
                bf16x8 f0 = *(const bf16x8*)&lds[arow + s4 + kb * 32];
                bf16x8 f1 = *(const bf16x8*)&lds[arow + s4 + (kb + 1) * 32];
                a0 = __builtin_amdgcn_mfma_f32_16x16x32_bf16(f0, wres[8 + kb],     a0, 0, 0, 0);
                a1 = __builtin_amdgcn_mfma_f32_16x16x32_bf16(f1, wres[8 + kb + 1], a1, 0, 0, 0);
            }
            float4v P = a0 + a1;
#pragma unroll
            for (int r = 0; r < 4; ++r) P[r] += uu[r];
            *(float4v*)&ring[(size_t)(t & 3) * 4096 + (tid << 2)] = P;   // plain store

            __syncthreads();   // drain P stores (vmcnt 0)
            if (tid == 0) {
                FENCE_REL();
                AS(&fl[1], (unsigned)(t + 1));
            }
        }
    }
}

extern "C" void kernel_launch(void* const* d_in, const int* in_sizes, int n_in,
                              void* d_out, int out_size, void* d_ws, size_t ws_size,
                              hipStream_t stream) {
    const float* o  = (const float*)d_in[0];
    const float* a  = (const float*)d_in[1];
    const float* W  = (const float*)d_in[2];
    const float* b  = (const float*)d_in[3];
    short*    Wb    = (short*)d_ws;                               // 768 KB packed W
    unsigned* flags = (unsigned*)((char*)d_ws + 786432);          // 4 KB flags
    float*    pring = (float*)((char*)d_ws + 790528);             // 4 MB partial rings

    hipLaunchKernelGGL(wprep_kernel, dim3(192), dim3(256), 0, stream, W, Wb, flags);
    hipLaunchKernelGGL(ugemm_kernel, dim3(1024), dim3(256), 0, stream,
                       o, a, b, Wb, (float*)d_out);
    hipLaunchKernelGGL(hist_kernel, dim3(128), dim3(1024), 0, stream,
                       Wb, flags, pring, (float*)d_out);
}

// Round 7
// 311.540 us; speedup vs baseline: 1.5824x; 1.5824x over previous
//
#include <hip/hip_runtime.h>

// ---- shapes (hard-coded to this problem) ----
#define TT 64
#define SLOT 320          // OUT + ACT
#define CONCAT 1536       // IN + 4*SLOT
#define XROW 520          // ugemm staging row: 512 + 8 pad

typedef __attribute__((ext_vector_type(8))) short bf16x8;
typedef __attribute__((ext_vector_type(4))) short short4v;
typedef __attribute__((ext_vector_type(4))) float float4v;

// flags: relaxed agent-scope atomics (the ONLY atomics).
// shared DATA: per-instruction coherent ld/st (sc0 sc1 = bypass L1+L2, r/w at the
// coherence point) -- NO cache-wide fences (R6's wbl2/inv storms were the wall).
#define AL(p)    __hip_atomic_load((p), __ATOMIC_RELAXED, __HIP_MEMORY_SCOPE_AGENT)
#define AS(p, v) __hip_atomic_store((p), (v), __ATOMIC_RELAXED, __HIP_MEMORY_SCOPE_AGENT)
#define SPIN_PAUSE __builtin_amdgcn_s_sleep(2)
#define DRAIN() asm volatile("s_waitcnt vmcnt(0)" ::: "memory")

__device__ __forceinline__ float4v ldc4(const float* p) {   // coherent 16B load
    float4v v;
    asm volatile("global_load_dwordx4 %0, %1, off sc0 sc1\n\ts_waitcnt vmcnt(0)"
                 : "=&v"(v) : "v"(p) : "memory");
    return v;
}
__device__ __forceinline__ void stc4(float* p, float4v v) {  // coherent 16B store
    asm volatile("global_store_dwordx4 %0, %1, off sc0 sc1" :: "v"(p), "v"(v) : "memory");
}
__device__ __forceinline__ void stc1(float* p, float v) {    // coherent 4B store
    asm volatile("global_store_dword %0, %1, off sc0 sc1" :: "v"(p), "v"(v) : "memory");
}

__device__ __forceinline__ short f2bf(float f) {
    union { float f; unsigned u; } v;
    v.f = f;
    unsigned r = v.u + 0x7fffu + ((v.u >> 16) & 1u);  // RNE
    return (short)(r >> 16);
}

// Repack W (256 x 1536 fp32) into bf16 MFMA-B-fragment streams:
//  sec 0..3 (64K shorts each): tap h=sec+1 -> A_h = W[:, (3-sec)*320 .. +255]
//                              [tl 0..15][kb 0..7][lane][8]
//  Wao at short offset 262144: [tl 0..15][kb 0..15][lane][8] over a-hist+o cols
// Also resets the sync flags (runs before hist on the same stream).
__global__ void wprep_kernel(const float* __restrict__ W, short* __restrict__ Wb,
                             unsigned* __restrict__ flags) {
    if (blockIdx.x == 0) {
        for (int i = threadIdx.x; i < 1024; i += 256) flags[i] = 0u;
    }
    int idx = blockIdx.x * 256 + threadIdx.x;       // 0 .. 49151
    if (idx >= 49152) return;
    int lane = idx & 63;
    int q = lane >> 4, ln = lane & 15;
    int n, col;
    if (idx < 32768) {              // tap sections
        int sec = idx >> 13;                        // 0..3
        int rem = idx & 8191;
        int tl = rem >> 9, kb = (rem >> 6) & 7;
        n = tl * 16 + ln;
        col = (3 - sec) * SLOT + kb * 32 + q * 8;   // A_1 at 960, A_4 at 0
    } else {                        // ao-part (for ugemm)
        int idx3 = idx - 32768;
        int tl = idx3 >> 10, kb = (idx3 >> 6) & 15;
        n = tl * 16 + ln;
        int ka = kb * 32 + q * 8;                   // 0..511
        col = (ka < 256) ? ((ka >> 6) * SLOT + 256 + (ka & 63))  // a-slot cols
                         : (1024 + ka);                          // o cols 1280..
    }
    const float* src = W + (size_t)n * CONCAT + col;
    short4v s0, s1;
    s0.x = f2bf(src[0]); s0.y = f2bf(src[1]); s0.z = f2bf(src[2]); s0.w = f2bf(src[3]);
    s1.x = f2bf(src[4]); s1.y = f2bf(src[5]); s1.z = f2bf(src[6]); s1.w = f2bf(src[7]);
    short* dst = Wb + (size_t)idx * 8;
    *(short4v*)dst = s0;
    *(short4v*)(dst + 4) = s1;
}

// Parallel precompute: u = W_ao * [a_hist | o] + b for ALL 65536 tokens, written
// into out (sequential kernel reads u then overwrites with z in-place).
__global__ __launch_bounds__(256) void ugemm_kernel(
    const float* __restrict__ o,    // (B,T,P,256)
    const float* __restrict__ act,  // (B,T,P,64)
    const float* __restrict__ bias, // (256)
    const short* __restrict__ Wb,   // tap secs + Wao
    float* __restrict__ out)        // (B,T,P,256) <- u
{
    __shared__ short xp[64 * XROW];   // 66560 B

    const int tid = threadIdx.x;
    const int wg  = blockIdx.x;       // b = wg>>6, t = wg&63
    const int b   = wg >> 6, t = wg & 63;
    const size_t tau0 = (size_t)wg * 64;

#pragma unroll
    for (int h = 0; h < 4; ++h) {
        int tp = t - 4 + h;
        const float* ap = act + (((size_t)b * 64 + tp) * 64) * 64;
        for (int f = tid; f < 1024; f += 256) {
            int p = f >> 4, c4 = (f & 15) << 2;
            short4v s;
            if (tp >= 0) {
                float4v v = *(const float4v*)(ap + p * 64 + c4);
                s.x = f2bf(v.x); s.y = f2bf(v.y); s.z = f2bf(v.z); s.w = f2bf(v.w);
            } else { s.x = 0; s.y = 0; s.z = 0; s.w = 0; }
            *(short4v*)&xp[p * XROW + h * 64 + c4] = s;
        }
    }
    {
        const float* op = o + tau0 * 256;
        for (int f = tid; f < 4096; f += 256) {
            int p = f >> 6, c4 = (f & 63) << 2;
            float4v v = *(const float4v*)(op + p * 256 + c4);
            short4v s;
            s.x = f2bf(v.x); s.y = f2bf(v.y); s.z = f2bf(v.z); s.w = f2bf(v.w);
            *(short4v*)&xp[p * XROW + 256 + c4] = s;
        }
    }
    __syncthreads();

    const int wv = tid >> 6, lane = tid & 63, q = lane >> 4, ln = lane & 15;
    const short* wao = Wb + 262144;

    float4v acc[4][4];
#pragma unroll
    for (int m = 0; m < 4; ++m)
#pragma unroll
        for (int i = 0; i < 4; ++i)
            acc[m][i] = (float4v){0.f, 0.f, 0.f, 0.f};

#pragma unroll
    for (int kb = 0; kb < 16; ++kb) {
        bf16x8 bf[4];
#pragma unroll
        for (int i = 0; i < 4; ++i)
            bf[i] = *(const bf16x8*)(wao + (((size_t)(4 * wv + i) * 16 + kb) * 64 + lane) * 8);
#pragma unroll
        for (int m = 0; m < 4; ++m) {
            bf16x8 af = *(const bf16x8*)&xp[(m * 16 + ln) * XROW + kb * 32 + q * 8];
#pragma unroll
            for (int i = 0; i < 4; ++i)
                acc[m][i] = __builtin_amdgcn_mfma_f32_16x16x32_bf16(af, bf[i], acc[m][i], 0, 0, 0);
        }
    }

#pragma unroll
    for (int i = 0; i < 4; ++i) {
        float bv = bias[(4 * wv + i) * 16 + ln];
#pragma unroll
        for (int m = 0; m < 4; ++m)
#pragma unroll
            for (int r = 0; r < 4; ++r)
                out[(tau0 + m * 16 + q * 4 + r) * 256 + (4 * wv + i) * 16 + ln] = acc[m][i][r] + bv;
    }
}

// Sequential kernel, 2-WG teams (128 WGs total, 1 WG/CU via 90KB LDS).
// team = blk&63 (16 seqs), role = blk>>6: 0 = FRONT (A1,A2 resident; z(t-1),z(t-2)
// from own LDS history), 1 = HELPER (A3,A4 resident; stages z(t-3) coherently with
// 3 steps of slack, keeps z(t-4) in LDS double-buffer, folds u(t); publishes
// P34(t) = A3 z(t-3) + A4 z(t-4) + u(t) through a depth-4 ring).
// Flags (per team): fl[0] = front z-step count, fl[1] = helper P count.
// Shared data: sc0sc1 write-through stores + bypass loads (no stale caches, no
// fences); vmcnt(0) drain + __syncthreads before each flag publish.
// Ring depth 4 safe: helper waited fl[0] >= t-2 => front finished t-3 => slot t&3
// consumed. Helper reads u(t) (plain cached: line never previously touched, and
// the read happens-before front's z(t) overwrite via P-publish ordering).
__global__ __launch_bounds__(1024, 4) void hist_kernel(
    const short* __restrict__ Wpk,
    unsigned* __restrict__ flags,
    float* __restrict__ pring,
    float* out)
{
    __shared__ short lds[45056];   // 90112 B: forces 1 WG/CU (co-residency guarantee)

    const int tid  = threadIdx.x;
    const int wave = tid >> 6;
    const int lane = tid & 63;
    const int q    = lane >> 4;
    const int ln   = lane & 15;
    const int team = blockIdx.x & 63;
    const int role = blockIdx.x >> 6;          // 0=front 1=helper
    const int bb   = team >> 2;
    const int p0   = (team & 3) << 4;
    unsigned* fl = flags + team * 16;
    float* outb = out + (((size_t)bb * 64) * 64 + p0) * 256;
    float* ring = pring + (size_t)team * 16384;   // 4 slots x 4096 floats
    const int n = (wave << 4) + ln;
    const int arow = ln * 520 + (q << 3);

    // resident tap matrices: role 0 -> A1,A2 (secs 0,1); role 1 -> A3,A4 (secs 2,3)
    // wave holds N-tile 'wave' x K=256 per tap: 16 frags = 64 VGPR
    bf16x8 wres[16];
    {
        const short* wp = Wpk + (size_t)(role * 2) * 65536
                              + ((size_t)(wave * 8) * 64 + lane) * 8;
#pragma unroll
        for (int kb = 0; kb < 8; ++kb) {
            wres[kb]     = *(const bf16x8*)(wp + kb * 512);
            wres[kb + 8] = *(const bf16x8*)(wp + 65536 + kb * 512);
        }
    }

    // zero the [16 rows][2 slots x 256 + 8 pad] bf16 history/staging region
    for (int i = tid; i < 4160; i += 1024) ((float*)lds)[i] = 0.f;
    __syncthreads();

    if (role == 0) {
        // ---------------- FRONT: z(t) = A1 z(t-1) + A2 z(t-2) + P34(t) ----------------
        for (int t = 0; t < TT; ++t) {
            const int s1 = ((t + 1) & 1) << 8;   // slot of z(t-1)
            const int s2 = (t & 1) << 8;         // slot of z(t-2) (rewritten with z(t))
            float4v a0 = {0.f, 0.f, 0.f, 0.f}, a1 = a0;
#pragma unroll
            for (int kb = 0; kb < 8; kb += 2) {
                bf16x8 f0 = *(const bf16x8*)&lds[arow + s1 + kb * 32];
                bf16x8 f1 = *(const bf16x8*)&lds[arow + s1 + (kb + 1) * 32];
                a0 = __builtin_amdgcn_mfma_f32_16x16x32_bf16(f0, wres[kb],     a0, 0, 0, 0);
                a1 = __builtin_amdgcn_mfma_f32_16x16x32_bf16(f1, wres[kb + 1], a1, 0, 0, 0);
            }
#pragma unroll
            for (int kb = 0; kb < 8; kb += 2) {
                bf16x8 f0 = *(const bf16x8*)&lds[arow + s2 + kb * 32];
                bf16x8 f1 = *(const bf16x8*)&lds[arow + s2 + (kb + 1) * 32];
                a0 = __builtin_amdgcn_mfma_f32_16x16x32_bf16(f0, wres[8 + kb],     a0, 0, 0, 0);
                a1 = __builtin_amdgcn_mfma_f32_16x16x32_bf16(f1, wres[8 + kb + 1], a1, 0, 0, 0);
            }
            if (tid == 0) {
                while (AL(&fl[1]) < (unsigned)(t + 1)) SPIN_PAUSE;
            }
            __syncthreads();   // P(t) published; all A-reads of slot s2 done
            const float4v P = ldc4(&ring[(size_t)(t & 3) * 4096 + (tid << 2)]);
            float4v z = (a0 + a1) + P;
            float* outp = outb + (size_t)t * 16384;
#pragma unroll
            for (int r = 0; r < 4; ++r) {
                const int m = (q << 2) + r;
                stc1(&outp[m * 256 + n], z[r]);           // write-through z
                lds[m * 520 + s2 + n] = f2bf(z[r]);       // z(t) -> slot t&1
            }
            DRAIN();           // z at coherence point
            __syncthreads();   // all threads drained + LDS ordered for next step
            if (tid == 0) AS(&fl[0], (unsigned)(t + 1));
        }
    } else {
        // ---------------- HELPER: P34(t) = A3 z(t-3) + A4 z(t-4) + u(t) ----------------
        for (int t = 0; t < TT; ++t) {
            // read u(t) (plain cached; happens-before front's z(t) overwrite)
            const float* up = outb + (size_t)t * 16384;
            float uu[4];
#pragma unroll
            for (int r = 0; r < 4; ++r) uu[r] = up[((q << 2) + r) * 256 + n];

            if (t >= 3) {
                if (tid == 0) {
                    while (AL(&fl[0]) < (unsigned)(t - 2)) SPIN_PAUSE;   // z(t-3) ready
                }
                __syncthreads();
                // stage z(t-3) -> LDS slot (t-3)&1 (bf16); z(t-4) kept from last step
                const float* zp = outb + (size_t)(t - 3) * 16384;
                const int row = tid >> 6, c4 = (tid & 63) << 2;
                float4v zv = ldc4(zp + row * 256 + c4);   // bypass (u(t-3) lines stale)
                short4v s;
                s.x = f2bf(zv.x); s.y = f2bf(zv.y); s.z = f2bf(zv.z); s.w = f2bf(zv.w);
                *(short4v*)&lds[row * 520 + (((t - 3) & 1) << 8) + c4] = s;
            }
            __syncthreads();   // staged z visible to all waves

            const int s3 = ((t + 1) & 1) << 8;   // slot of z(t-3)  ((t-3)&1 == (t+1)&1)
            const int s4 = (t & 1) << 8;         // slot of z(t-4)
            float4v a0 = {0.f, 0.f, 0.f, 0.f}, a1 = a0;
#pragma unroll
            for (int kb = 0; kb < 8; kb += 2) {
                bf16x8 f0 = *(const bf16x8*)&lds[arow + s3 + kb * 32];
                bf16x8 f1 = *(const bf16x8*)&lds[arow + s3 + (kb + 1) * 32];
                a0 = __builtin_amdgcn_mfma_f32_16x16x32_bf16(f0, wres[kb],     a0, 0, 0, 0);
                a1 = __builtin_amdgcn_mfma_f32_16x16x32_bf16(f1, wres[kb + 1], a1, 0, 0, 0);
            }
#pragma unroll
            for (int kb = 0; kb < 8; kb += 2) {
                bf16x8 f0 = *(const bf16x8*)&lds[arow + s4 + kb * 32];
                bf16x8 f1 = *(const bf16x8*)&lds[arow + s4 + (kb + 1) * 32];
                a0 = __builtin_amdgcn_mfma_f32_16x16x32_bf16(f0, wres[8 + kb],     a0, 0, 0, 0);
                a1 = __builtin_amdgcn_mfma_f32_16x16x32_bf16(f1, wres[8 + kb + 1], a1, 0, 0, 0);
            }
            float4v P = a0 + a1;
#pragma unroll
            for (int r = 0; r < 4; ++r) P[r] += uu[r];
            stc4(&ring[(size_t)(t & 3) * 4096 + (tid << 2)], P);   // write-through P

            DRAIN();           // P at coherence point
            __syncthreads();
            if (tid == 0) AS(&fl[1], (unsigned)(t + 1));
        }
    }
}

extern "C" void kernel_launch(void* const* d_in, const int* in_sizes, int n_in,
                              void* d_out, int out_size, void* d_ws, size_t ws_size,
                              hipStream_t stream) {
    const float* o  = (const float*)d_in[0];
    const float* a  = (const float*)d_in[1];
    const float* W  = (const float*)d_in[2];
    const float* b  = (const float*)d_in[3];
    short*    Wb    = (short*)d_ws;                               // 768 KB packed W
    unsigned* flags = (unsigned*)((char*)d_ws + 786432);          // 4 KB flags
    float*    pring = (float*)((char*)d_ws + 790528);             // 4 MB partial rings

    hipLaunchKernelGGL(wprep_kernel, dim3(192), dim3(256), 0, stream, W, Wb, flags);
    hipLaunchKernelGGL(ugemm_kernel, dim3(1024), dim3(256), 0, stream,
                       o, a, b, Wb, (float*)d_out);
    hipLaunchKernelGGL(hist_kernel, dim3(128), dim3(1024), 0, stream,
                       Wb, flags, pring, (float*)d_out);
}

// Round 8
// 301.643 us; speedup vs baseline: 1.6343x; 1.0328x over previous
//
#include <hip/hip_runtime.h>

// ---- shapes (hard-coded to this problem) ----
#define TT 64
#define SLOT 320          // OUT + ACT
#define CONCAT 1536       // IN + 4*SLOT
#define XROW 520          // ugemm staging row: 512 + 8 pad

typedef __attribute__((ext_vector_type(8))) short bf16x8;
typedef __attribute__((ext_vector_type(4))) short short4v;
typedef __attribute__((ext_vector_type(4))) float float4v;

// flags: relaxed agent-scope atomics (the ONLY atomics).
// shared DATA: per-instruction coherent ld/st (sc0 sc1 = bypass L1+L2, r/w at the
// coherence point) -- NO cache-wide fences.
#define AL(p)    __hip_atomic_load((p), __ATOMIC_RELAXED, __HIP_MEMORY_SCOPE_AGENT)
#define AS(p, v) __hip_atomic_store((p), (v), __ATOMIC_RELAXED, __HIP_MEMORY_SCOPE_AGENT)
#define SPIN_PAUSE __builtin_amdgcn_s_sleep(1)
#define DRAIN() asm volatile("s_waitcnt vmcnt(0)" ::: "memory")
// rule #18: after an asm waitcnt, fence the scheduler so register consumers
// of asm-load results can't be hoisted above the wait.
#define VWAIT() do { asm volatile("s_waitcnt vmcnt(0)" ::: "memory"); \
                     __builtin_amdgcn_sched_barrier(0); } while (0)

// non-blocking coherent 16B load (consume only after VWAIT())
__device__ __forceinline__ void ldc4i(const float* p, float4v& v) {
    asm volatile("global_load_dwordx4 %0, %1, off sc0 sc1"
                 : "=&v"(v) : "v"(p) : "memory");
}
__device__ __forceinline__ void stc4(float* p, float4v v) {  // coherent 16B store
    asm volatile("global_store_dwordx4 %0, %1, off sc0 sc1" :: "v"(p), "v"(v) : "memory");
}
__device__ __forceinline__ void stc1(float* p, float v) {    // coherent 4B store
    asm volatile("global_store_dword %0, %1, off sc0 sc1" :: "v"(p), "v"(v) : "memory");
}

__device__ __forceinline__ short f2bf(float f) {
    union { float f; unsigned u; } v;
    v.f = f;
    unsigned r = v.u + 0x7fffu + ((v.u >> 16) & 1u);  // RNE
    return (short)(r >> 16);
}

// Repack W (256 x 1536 fp32) into bf16 MFMA-B-fragment streams:
//  sec 0..3 (64K shorts each): tap h=sec+1 -> A_h = W[:, (3-sec)*320 .. +255]
//                              [tl 0..15][kb 0..7][lane][8]
//  Wao at short offset 262144: [tl 0..15][kb 0..15][lane][8] over a-hist+o cols
// Also resets the sync flags (runs before hist on the same stream).
__global__ void wprep_kernel(const float* __restrict__ W, short* __restrict__ Wb,
                             unsigned* __restrict__ flags) {
    if (blockIdx.x == 0) {
        for (int i = threadIdx.x; i < 1024; i += 256) flags[i] = 0u;
    }
    int idx = blockIdx.x * 256 + threadIdx.x;       // 0 .. 49151
    if (idx >= 49152) return;
    int lane = idx & 63;
    int q = lane >> 4, ln = lane & 15;
    int n, col;
    if (idx < 32768) {              // tap sections
        int sec = idx >> 13;                        // 0..3
        int rem = idx & 8191;
        int tl = rem >> 9, kb = (rem >> 6) & 7;
        n = tl * 16 + ln;
        col = (3 - sec) * SLOT + kb * 32 + q * 8;   // A_1 at 960, A_4 at 0
    } else {                        // ao-part (for ugemm)
        int idx3 = idx - 32768;
        int tl = idx3 >> 10, kb = (idx3 >> 6) & 15;
        n = tl * 16 + ln;
        int ka = kb * 32 + q * 8;                   // 0..511
        col = (ka < 256) ? ((ka >> 6) * SLOT + 256 + (ka & 63))  // a-slot cols
                         : (1024 + ka);                          // o cols 1280..
    }
    const float* src = W + (size_t)n * CONCAT + col;
    short4v s0, s1;
    s0.x = f2bf(src[0]); s0.y = f2bf(src[1]); s0.z = f2bf(src[2]); s0.w = f2bf(src[3]);
    s1.x = f2bf(src[4]); s1.y = f2bf(src[5]); s1.z = f2bf(src[6]); s1.w = f2bf(src[7]);
    short* dst = Wb + (size_t)idx * 8;
    *(short4v*)dst = s0;
    *(short4v*)(dst + 4) = s1;
}

// Parallel precompute: u = W_ao * [a_hist | o] + b for ALL 65536 tokens, written
// into out (sequential kernel reads u then overwrites with z in-place).
__global__ __launch_bounds__(256) void ugemm_kernel(
    const float* __restrict__ o,    // (B,T,P,256)
    const float* __restrict__ act,  // (B,T,P,64)
    const float* __restrict__ bias, // (256)
    const short* __restrict__ Wb,   // tap secs + Wao
    float* __restrict__ out)        // (B,T,P,256) <- u
{
    __shared__ short xp[64 * XROW];   // 66560 B

    const int tid = threadIdx.x;
    const int wg  = blockIdx.x;       // b = wg>>6, t = wg&63
    const int b   = wg >> 6, t = wg & 63;
    const size_t tau0 = (size_t)wg * 64;

#pragma unroll
    for (int h = 0; h < 4; ++h) {
        int tp = t - 4 + h;
        const float* ap = act + (((size_t)b * 64 + tp) * 64) * 64;
        for (int f = tid; f < 1024; f += 256) {
            int p = f >> 4, c4 = (f & 15) << 2;
            short4v s;
            if (tp >= 0) {
                float4v v = *(const float4v*)(ap + p * 64 + c4);
                s.x = f2bf(v.x); s.y = f2bf(v.y); s.z = f2bf(v.z); s.w = f2bf(v.w);
            } else { s.x = 0; s.y = 0; s.z = 0; s.w = 0; }
            *(short4v*)&xp[p * XROW + h * 64 + c4] = s;
        }
    }
    {
        const float* op = o + tau0 * 256;
        for (int f = tid; f < 4096; f += 256) {
            int p = f >> 6, c4 = (f & 63) << 2;
            float4v v = *(const float4v*)(op + p * 256 + c4);
            short4v s;
            s.x = f2bf(v.x); s.y = f2bf(v.y); s.z = f2bf(v.z); s.w = f2bf(v.w);
            *(short4v*)&xp[p * XROW + 256 + c4] = s;
        }
    }
    __syncthreads();

    const int wv = tid >> 6, lane = tid & 63, q = lane >> 4, ln = lane & 15;
    const short* wao = Wb + 262144;

    float4v acc[4][4];
#pragma unroll
    for (int m = 0; m < 4; ++m)
#pragma unroll
        for (int i = 0; i < 4; ++i)
            acc[m][i] = (float4v){0.f, 0.f, 0.f, 0.f};

#pragma unroll
    for (int kb = 0; kb < 16; ++kb) {
        bf16x8 bf[4];
#pragma unroll
        for (int i = 0; i < 4; ++i)
            bf[i] = *(const bf16x8*)(wao + (((size_t)(4 * wv + i) * 16 + kb) * 64 + lane) * 8);
#pragma unroll
        for (int m = 0; m < 4; ++m) {
            bf16x8 af = *(const bf16x8*)&xp[(m * 16 + ln) * XROW + kb * 32 + q * 8];
#pragma unroll
            for (int i = 0; i < 4; ++i)
                acc[m][i] = __builtin_amdgcn_mfma_f32_16x16x32_bf16(af, bf[i], acc[m][i], 0, 0, 0);
        }
    }

#pragma unroll
    for (int i = 0; i < 4; ++i) {
        float bv = bias[(4 * wv + i) * 16 + ln];
#pragma unroll
        for (int m = 0; m < 4; ++m)
#pragma unroll
            for (int r = 0; r < 4; ++r)
                out[(tau0 + m * 16 + q * 4 + r) * 256 + (4 * wv + i) * 16 + ln] = acc[m][i][r] + bv;
    }
}

// Sequential kernel, 2-WG teams (128 WGs, 1 WG/CU via 90KB LDS), SOFTWARE-PIPELINED.
// Roles as R7. Flag semantics (pipelined): fl[0] = v  <=>  z(0..v-1) at coherence
// point (front publishes fl[0]=t at step t, covering z(t-1) drained by the shared
// vmcnt(0)). fl[1] = v <=> P(0..v-1) published.
// FRONT step t: wait fl[1]>=t+1 (helper's gate for P(t) was fl[0]>=t-2, satisfied
// two front-steps ago -> acyclic); issue P(t) load non-blocking; MFMA under it;
// one vmcnt(0) drains BOTH prev z stores and P; publish fl[0]=t; z stores (no
// drain). HELPER step t: issue z(t-3) stage load non-blocking; A4 MFMAs (z(t-4)
// already in LDS) under it; convert+stage; A3 MFMAs; P publish prompt.
__global__ __launch_bounds__(1024, 4) void hist_kernel(
    const short* __restrict__ Wpk,
    unsigned* __restrict__ flags,
    float* __restrict__ pring,
    float* out)
{
    __shared__ short lds[45056];   // 90112 B: forces 1 WG/CU (co-residency guarantee)

    const int tid  = threadIdx.x;
    const int wave = tid >> 6;
    const int lane = tid & 63;
    const int q    = lane >> 4;
    const int ln   = lane & 15;
    const int team = blockIdx.x & 63;
    const int role = blockIdx.x >> 6;          // 0=front 1=helper
    const int bb   = team >> 2;
    const int p0   = (team & 3) << 4;
    unsigned* fl = flags + team * 16;
    float* outb = out + (((size_t)bb * 64) * 64 + p0) * 256;
    float* ring = pring + (size_t)team * 16384;   // 4 slots x 4096 floats
    const int n = (wave << 4) + ln;
    const int arow = ln * 520 + (q << 3);

    // resident tap matrices: role 0 -> A1,A2 (secs 0,1); role 1 -> A3,A4 (secs 2,3)
    bf16x8 wres[16];
    {
        const short* wp = Wpk + (size_t)(role * 2) * 65536
                              + ((size_t)(wave * 8) * 64 + lane) * 8;
#pragma unroll
        for (int kb = 0; kb < 8; ++kb) {
            wres[kb]     = *(const bf16x8*)(wp + kb * 512);
            wres[kb + 8] = *(const bf16x8*)(wp + 65536 + kb * 512);
        }
    }

    // zero the [16 rows][2 slots x 256 + 8 pad] bf16 history/staging region
    for (int i = tid; i < 4160; i += 1024) ((float*)lds)[i] = 0.f;
    __syncthreads();

    if (role == 0) {
        // ---------------- FRONT: z(t) = A1 z(t-1) + A2 z(t-2) + P34(t) ----------------
        for (int t = 0; t < TT; ++t) {
            if (tid == 0) {
                while (AL(&fl[1]) < (unsigned)(t + 1)) SPIN_PAUSE;
            }
            __syncthreads();   // P(t) published; prev-iter LDS hist writes visible
            float4v P;
            ldc4i(&ring[(size_t)(t & 3) * 4096 + (tid << 2)], P);   // issue (no wait)

            const int s1 = ((t + 1) & 1) << 8;   // slot of z(t-1)
            const int s2 = (t & 1) << 8;         // slot of z(t-2) (rewritten with z(t))
            float4v a0 = {0.f, 0.f, 0.f, 0.f}, a1 = a0;
#pragma unroll
            for (int kb = 0; kb < 8; kb += 2) {
                bf16x8 f0 = *(const bf16x8*)&lds[arow + s1 + kb * 32];
                bf16x8 f1 = *(const bf16x8*)&lds[arow + s1 + (kb + 1) * 32];
                a0 = __builtin_amdgcn_mfma_f32_16x16x32_bf16(f0, wres[kb],     a0, 0, 0, 0);
                a1 = __builtin_amdgcn_mfma_f32_16x16x32_bf16(f1, wres[kb + 1], a1, 0, 0, 0);
            }
#pragma unroll
            for (int kb = 0; kb < 8; kb += 2) {
                bf16x8 f0 = *(const bf16x8*)&lds[arow + s2 + kb * 32];
                bf16x8 f1 = *(const bf16x8*)&lds[arow + s2 + (kb + 1) * 32];
                a0 = __builtin_amdgcn_mfma_f32_16x16x32_bf16(f0, wres[8 + kb],     a0, 0, 0, 0);
                a1 = __builtin_amdgcn_mfma_f32_16x16x32_bf16(f1, wres[8 + kb + 1], a1, 0, 0, 0);
            }

            VWAIT();           // P arrived + prev z(t-1) stores at coherence point
            __syncthreads();   // all threads drained
            if (tid == 0) AS(&fl[0], (unsigned)t);   // publish z(t-1)

            float4v z = (a0 + a1) + P;
            float* outp = outb + (size_t)t * 16384;
#pragma unroll
            for (int r = 0; r < 4; ++r) {
                const int m = (q << 2) + r;
                stc1(&outp[m * 256 + n], z[r]);           // write-through (drained next iter)
                lds[m * 520 + s2 + n] = f2bf(z[r]);       // z(t) -> slot t&1
            }
            // no trailing barrier: next iter's top sync orders these LDS writes
        }
        DRAIN();               // final z(63) at coherence point before kernel end
    } else {
        // ---------------- HELPER: P34(t) = A3 z(t-3) + A4 z(t-4) + u(t) ----------------
        const int row = tid >> 6, c4 = (tid & 63) << 2;
        for (int t = 0; t < TT; ++t) {
            // u(t) (plain cached; consumed before P publish => before front's z(t))
            const float* up = outb + (size_t)t * 16384;
            float uu[4];
#pragma unroll
            for (int r = 0; r < 4; ++r) uu[r] = up[((q << 2) + r) * 256 + n];

            if (tid == 0 && t >= 3) {
                while (AL(&fl[0]) < (unsigned)(t - 2)) SPIN_PAUSE;   // z(t-3) ready
            }
            __syncthreads();
            float4v zv;
            if (t >= 3)
                ldc4i(outb + (size_t)(t - 3) * 16384 + row * 256 + c4, zv);  // issue

            const int s3 = ((t + 1) & 1) << 8;   // slot of z(t-3)
            const int s4 = (t & 1) << 8;         // slot of z(t-4)
            float4v a0 = {0.f, 0.f, 0.f, 0.f}, a1 = a0;
            // A4 half first: z(t-4) staged last iteration, already in LDS
#pragma unroll
            for (int kb = 0; kb < 8; kb += 2) {
                bf16x8 f0 = *(const bf16x8*)&lds[arow + s4 + kb * 32];
                bf16x8 f1 = *(const bf16x8*)&lds[arow + s4 + (kb + 1) * 32];
                a0 = __builtin_amdgcn_mfma_f32_16x16x32_bf16(f0, wres[8 + kb],     a0, 0, 0, 0);
                a1 = __builtin_amdgcn_mfma_f32_16x16x32_bf16(f1, wres[8 + kb + 1], a1, 0, 0, 0);
            }
            if (t >= 3) {       // stage z(t-3) -> LDS slot s3 (load overlapped A4 MFMAs)
                VWAIT();
                short4v s;
                s.x = f2bf(zv.x); s.y = f2bf(zv.y); s.z = f2bf(zv.z); s.w = f2bf(zv.w);
                *(short4v*)&lds[row * 520 + s3 + c4] = s;
            }
            __syncthreads();    // staged z(t-3) visible
#pragma unroll
            for (int kb = 0; kb < 8; kb += 2) {
                bf16x8 f0 = *(const bf16x8*)&lds[arow + s3 + kb * 32];
                bf16x8 f1 = *(const bf16x8*)&lds[arow + s3 + (kb + 1) * 32];
                a0 = __builtin_amdgcn_mfma_f32_16x16x32_bf16(f0, wres[kb],     a0, 0, 0, 0);
                a1 = __builtin_amdgcn_mfma_f32_16x16x32_bf16(f1, wres[kb + 1], a1, 0, 0, 0);
            }
            float4v P = a0 + a1;
#pragma unroll
            for (int r = 0; r < 4; ++r) P[r] += uu[r];
            stc4(&ring[(size_t)(t & 3) * 4096 + (tid << 2)], P);

            DRAIN();            // P at coherence point
            __syncthreads();
            if (tid == 0) AS(&fl[1], (unsigned)(t + 1));
        }
    }
}

extern "C" void kernel_launch(void* const* d_in, const int* in_sizes, int n_in,
                              void* d_out, int out_size, void* d_ws, size_t ws_size,
                              hipStream_t stream) {
    const float* o  = (const float*)d_in[0];
    const float* a  = (const float*)d_in[1];
    const float* W  = (const float*)d_in[2];
    const float* b  = (const float*)d_in[3];
    short*    Wb    = (short*)d_ws;                               // 768 KB packed W
    unsigned* flags = (unsigned*)((char*)d_ws + 786432);          // 4 KB flags
    float*    pring = (float*)((char*)d_ws + 790528);             // 4 MB partial rings

    hipLaunchKernelGGL(wprep_kernel, dim3(192), dim3(256), 0, stream, W, Wb, flags);
    hipLaunchKernelGGL(ugemm_kernel, dim3(1024), dim3(256), 0, stream,
                       o, a, b, Wb, (float*)d_out);
    hipLaunchKernelGGL(hist_kernel, dim3(128), dim3(1024), 0, stream,
                       Wb, flags, pring, (float*)d_out);
}